// Round 8
// baseline (78.575 us; speedup 1.0000x reference)
//
#include <hip/hip_runtime.h>

#define G_TOTAL 16384            // 128 x 128 grid
#define NPTS    8192
#define CI      32               // context points per block (R7: 64)
#define NSPLIT  256              // 8192 / CI
#define BK      32               // k extent per block tile
#define PPLANES 24               // (cq 0..11) x (tj-half) planes of 256 half2
// ws: partials as half2 [4 tiles][256 s][24 planes][256] = 25.2 MB

typedef _Float16 h2 __attribute__((ext_vector_type(2)));

// Raw v_exp_f32 — args in [-30, 0]: no denormal/range fixup needed.
__device__ __forceinline__ float fast_exp2(float x) {
#if __has_builtin(__builtin_amdgcn_exp2f)
    return __builtin_amdgcn_exp2f(x);
#else
    float r; asm("v_exp_f32 %0, %1" : "=v"(r) : "v"(x)); return r;
#endif
}

// ---------------------------------------------------------------------------
// Fused factorized kernel (R7 core at doubled occupancy).
// R7 post-mortem: kernel-side 32.8 us of which enc ~26 vs ~10 us pipe model;
// grid 512 = 2 waves/SIMD can't hide ds_read latency under the 3-LDS-read ->
// 56-VALU dependency per i. This round: CI 64->32, grid 1024 = 4 blocks/CU
// = 4 waves/SIMD (LDS 20.3 KB). Inner loop/tile unchanged (measured-best).
// Cost: 25.2 MB fp16 partials (NSPLIT 256).
// ---------------------------------------------------------------------------
__global__ __launch_bounds__(256, 4) void enc_fused(
    const float* __restrict__ X,   // (8192, 2) positions
    const float* __restrict__ Y,   // (8192, 2) labels
    h2* __restrict__ wsP)          // partials [tile][s][plane][256]
{
    __shared__ float4 Ex4[CI][32];   // [i][jf] : j = 4*jf+tj     (16 KB)
    __shared__ float4 Ey4[CI][8];    // [i][kf] : k = kb+4*kf+tk  (4 KB)
    __shared__ float2 W2[CI];        // labels                    (0.25 KB)

    const int t    = threadIdx.x;
    const int b    = blockIdx.x;
    const int tile = b & 3;          // k band: kb = tile*32
    const int sidx = b >> 2;         // split 0..255
    const int c0   = sidx * CI;
    const int kb   = tile * BK;

    const float sc   = 0.84932184f;  // sqrt(0.5 * log2(e))
    const float step = 4.0f / 127.0f;
    const float ss   = step * sc;

    const float2* X2 = (const float2*)X;
    const float2* Y2 = (const float2*)Y;

    // ---- stage Ex: 32i x 128j, lane-consecutive float4 writes.
#pragma unroll
    for (int r = 0; r < 4; ++r) {
        const int   i  = r * 8 + (t >> 5);
        const int   jf = t & 31;
        const float sx = X2[c0 + i].x * sc;
        float d = (-2.0f + step * (float)(4 * jf)) * sc - sx;
        float4 v;
        v.x = fast_exp2(-d * d); d += ss;
        v.y = fast_exp2(-d * d); d += ss;
        v.z = fast_exp2(-d * d); d += ss;
        v.w = fast_exp2(-d * d);
        Ex4[i][jf] = v;
    }
    // ---- stage Ey: 32i x 32k; i = t>>3, kf = t&7. gy falls with k.
    {
        const int   i  = t >> 3;
        const int   kf = t & 7;
        const float sy = X2[c0 + i].y * sc;
        float d = (2.0f - step * (float)(kb + 4 * kf)) * sc - sy;
        float4 v;
        v.x = fast_exp2(-d * d); d -= ss;
        v.y = fast_exp2(-d * d); d -= ss;
        v.z = fast_exp2(-d * d); d -= ss;
        v.w = fast_exp2(-d * d);
        Ey4[i][kf] = v;
    }
    if (t < CI) W2[t] = Y2[c0 + t];
    __syncthreads();

    // ---- rank-1 accumulation: 48 independent fma chains.
    const int jf = t & 31;
    const int kf = t >> 5;

    float acc[48];                   // [(c*4+tk)][tj]
#pragma unroll
    for (int z = 0; z < 48; ++z) acc[z] = 0.0f;

#pragma unroll 4
    for (int i = 0; i < CI; ++i) {
        const float4 a = Ex4[i][jf];     // per-lane b128, conflict-free
        const float4 e = Ey4[i][kf];     // 2 addrs/wave -> broadcast
        const float2 w = W2[i];          // uniform b64
        const float av[4] = {a.x, a.y, a.z, a.w};
        const float ev[4] = {e.x, e.y, e.z, e.w};
#pragma unroll
        for (int tk = 0; tk < 4; ++tk) {
            const float et = ev[tk];
            const float m1 = et * w.x;
            const float m2 = et * w.y;
#pragma unroll
            for (int tj = 0; tj < 4; ++tj) {
                acc[(tk)*4      + tj] = fmaf(av[tj], et, acc[(tk)*4      + tj]);
                acc[(4 + tk)*4  + tj] = fmaf(av[tj], m1, acc[(4 + tk)*4  + tj]);
                acc[(8 + tk)*4  + tj] = fmaf(av[tj], m2, acc[(8 + tk)*4  + tj]);
            }
        }
    }

    // ---- fp16 packed partial store: plane p = cq*2 + half, lane-consecutive.
    h2* P = wsP + (size_t)((tile * NSPLIT + sidx) * PPLANES) * 256 + t;
#pragma unroll
    for (int cq = 0; cq < 12; ++cq) {
        h2 lo, hi;                       // RNE converts (unbiased)
        lo.x = (_Float16)acc[cq*4 + 0];  lo.y = (_Float16)acc[cq*4 + 1];
        hi.x = (_Float16)acc[cq*4 + 2];  hi.y = (_Float16)acc[cq*4 + 3];
        P[(cq*2 + 0) * 256] = lo;
        P[(cq*2 + 1) * 256] = hi;
    }
}

// ---------------------------------------------------------------------------
// Reduce + normalize v3, scaled for NSPLIT=256: 256 blocks x 256 threads.
// Block b = (tile, tk, half, uq): owns 32 u (all with kf=uq, jf=ul) => one k
// row, 64 j's. Thread (ul = t&31, sq = t>>5) sums 32 s x 3 channel planes,
// reads wave-aligned 128B segments; 8-way LDS combine; 32 lanes normalize
// + write float2.
// ---------------------------------------------------------------------------
__global__ __launch_bounds__(256) void reduce_norm(
    const h2* __restrict__ wsP, float* __restrict__ out)
{
    __shared__ float2 sm[3][8][32];      // [c][sq][ul] : 6 KB

    const int t    = threadIdx.x;
    const int ul   = t & 31;
    const int sq   = t >> 5;
    const int b    = blockIdx.x;
    const int tile = b >> 6;
    const int rem  = b & 63;
    const int tk   = rem >> 4;
    const int half = (rem >> 3) & 1;
    const int uq   = rem & 7;
    const int u    = uq * 32 + ul;       // writer-thread id (kf=uq, jf=ul)

    const int p0 = (0 * 4 + tk) * 2 + half;
    const int p1 = (1 * 4 + tk) * 2 + half;
    const int p2 = (2 * 4 + tk) * 2 + half;

    float2 s0 = make_float2(0.f, 0.f);
    float2 s1 = make_float2(0.f, 0.f);
    float2 s2 = make_float2(0.f, 0.f);

#pragma unroll 4
    for (int s = sq * 32; s < sq * 32 + 32; ++s) {
        const h2* q = wsP + (size_t)((tile * NSPLIT + s) * PPLANES) * 256 + u;
        const h2 a = q[p0 * 256];
        const h2 bb = q[p1 * 256];
        const h2 c = q[p2 * 256];
        s0.x += (float)a.x;   s0.y += (float)a.y;
        s1.x += (float)bb.x;  s1.y += (float)bb.y;
        s2.x += (float)c.x;   s2.y += (float)c.y;
    }
    sm[0][sq][ul] = s0;
    sm[1][sq][ul] = s1;
    sm[2][sq][ul] = s2;
    __syncthreads();

    if (t < 32) {
        float2 f0 = make_float2(0.f, 0.f);
        float2 f1 = make_float2(0.f, 0.f);
        float2 f2 = make_float2(0.f, 0.f);
#pragma unroll
        for (int w = 0; w < 8; ++w) {
            f0.x += sm[0][w][t].x;  f0.y += sm[0][w][t].y;
            f1.x += sm[1][w][t].x;  f1.y += sm[1][w][t].y;
            f2.x += sm[2][w][t].x;  f2.y += sm[2][w][t].y;
        }
        // u for this lane: kf = uq (block-uniform), jf = t
        const int k = tile * BK + uq * 4 + tk;
        const int j = t * 4 + half * 2;
        const int g = k * 128 + j;

        const float i0 = 1.0f / f0.x;
        const float i1 = 1.0f / f0.y;
        *(float2*)(out + g)             = make_float2(f0.x,      f0.y);
        *(float2*)(out + G_TOTAL + g)   = make_float2(f1.x * i0, f1.y * i1);
        *(float2*)(out + 2*G_TOTAL + g) = make_float2(f2.x * i0, f2.y * i1);
    }
}

// ---------------------------------------------------------------------------
extern "C" void kernel_launch(void* const* d_in, const int* in_sizes, int n_in,
                              void* d_out, int out_size, void* d_ws, size_t ws_size,
                              hipStream_t stream) {
    const float* X = (const float*)d_in[0];
    const float* Y = (const float*)d_in[1];
    float* out = (float*)d_out;
    h2*   wsP = (h2*)d_ws;

    enc_fused<<<1024, 256, 0, stream>>>(X, Y, wsP);    // 4 blocks/CU
    reduce_norm<<<256, 256, 0, stream>>>(wsP, out);
}

// Round 9
// 68.985 us; speedup vs baseline: 1.1390x; 1.1390x over previous
//
#include <hip/hip_runtime.h>

#define G_TOTAL 16384            // 128 x 128 grid
#define NPTS    8192
#define CI      64               // context points per block chunk
#define NSPLIT  128              // 8192 / CI
#define LDA     72               // LDS row pitch in halves (64 + 8 pad)
#define PBLK    12288            // partial halves per block: 4w x 12f x 64l x 4r

typedef _Float16 f16;
typedef f16  f16x8 __attribute__((ext_vector_type(8)));
typedef f16  f16x4 __attribute__((ext_vector_type(4)));
typedef float f32x4 __attribute__((ext_vector_type(4)));

// Raw v_exp_f32 — args in [-40, 0]: no denormal/range fixup needed.
__device__ __forceinline__ float fast_exp2(float x) {
#if __has_builtin(__builtin_amdgcn_exp2f)
    return __builtin_amdgcn_exp2f(x);
#else
    float r; asm("v_exp_f32 %0, %1" : "=v"(r) : "v"(x)); return r;
#endif
}

// ---------------------------------------------------------------------------
// MFMA factorized kernel. out[k,j,c] = sum_i Ey[k,i]*wc[i] * Ex[i,j]
// = 3 GEMMs of 128x128x8192 (805 MFLOP ~ 0.5us at f16 MFMA rate).
// R8 post-mortem: VALU inner loop stuck ~2.5x over issue floor regardless of
// occupancy/tile; MfmaUtil was 0 the whole session. Move contraction to
// v_mfma_f32_16x16x32_f16.
// Block (tile,sidx): k-band 32 x full 128 j x 3c over CI=64 points. 4 waves;
// wave w owns j in [32w,32w+32): acc = 2kt x 2jt x 3c fragments (48 VGPR).
// Layouts (m89-verified family): A[m][k]: m=l&15, k=(l>>4)*8+e; B[k][n]:
// n=l&15, same k; D: row=(l>>4)*4+r, col=l&15.
// LDS fp16 tiles, pitch 72 halves -> ~2-way banks on b128 frag reads (free).
// Partials stored fragment-native (lane-contiguous h4) -> coalesced store
// AND coalesced reduce ingest. 12.6 MB fp16, same as R7.
// ---------------------------------------------------------------------------
__global__ __launch_bounds__(256) void enc_mfma(
    const float* __restrict__ X,   // (8192, 2) positions
    const float* __restrict__ Y,   // (8192, 2) labels
    f16* __restrict__ wsP)         // partials [tile][s][PBLK]
{
    __shared__ f16 ExT[128 * LDA];     // [j][i]    18.4 KB
    __shared__ f16 Ey3[3 * 32 * LDA];  // [c][k][i] 13.8 KB

    const int t    = threadIdx.x;
    const int b    = blockIdx.x;
    const int tile = b & 3;            // k band: kb = tile*32
    const int sidx = b >> 2;           // split 0..127
    const int c0   = sidx * CI;
    const int kb   = tile * 32;

    const float sc   = 0.84932184f;    // sqrt(0.5 * log2(e))
    const float step = 4.0f / 127.0f;

    const float2* X2 = (const float2*)X;
    const float2* Y2 = (const float2*)Y;

    // ---- stage ExT[j][i], fp16: thread -> (j = t>>1, 32-i half)
    {
        const int   j  = t >> 1, ih = (t & 1) * 32;
        const float gx = (-2.0f + step * (float)j) * sc;
#pragma unroll
        for (int u = 0; u < 4; ++u) {
            f16x8 v;
#pragma unroll
            for (int e = 0; e < 8; ++e) {
                const int   i = ih + u * 8 + e;
                const float d = gx - X2[c0 + i].x * sc;
                v[e] = (f16)fast_exp2(-d * d);
            }
            *(f16x8*)&ExT[j * LDA + ih + u * 8] = v;
        }
    }
    // ---- stage Ey3[c][k][i], channels baked: thread -> (k = t>>3, 8-i block)
    {
        const int   k  = t >> 3, ib = (t & 7) * 8;
        const float gy = (2.0f - step * (float)(kb + k)) * sc;
        f16x8 v0, v1, v2;
#pragma unroll
        for (int e = 0; e < 8; ++e) {
            const int    i  = ib + e;
            const float  d  = gy - X2[c0 + i].y * sc;
            const float  ee = fast_exp2(-d * d);
            const float2 yv = Y2[c0 + i];
            v0[e] = (f16)ee;
            v1[e] = (f16)(ee * yv.x);
            v2[e] = (f16)(ee * yv.y);
        }
        *(f16x8*)&Ey3[(0 * 32 + k) * LDA + ib] = v0;
        *(f16x8*)&Ey3[(1 * 32 + k) * LDA + ib] = v1;
        *(f16x8*)&Ey3[(2 * 32 + k) * LDA + ib] = v2;
    }
    __syncthreads();

    // ---- MFMA: wave w, j-base 32w. 24 mfma_f32_16x16x32_f16 per wave.
    const int w    = t >> 6;
    const int lane = t & 63;
    const int l15  = lane & 15;
    const int lk8  = (lane >> 4) * 8;

    f32x4 acc[12];                     // [c*4 + kt*2 + jt]
#pragma unroll
    for (int z = 0; z < 12; ++z) acc[z] = (f32x4){0.f, 0.f, 0.f, 0.f};

#pragma unroll
    for (int ks = 0; ks < 2; ++ks) {
        const int io = ks * 32 + lk8;
        const f16x8 bf0 = *(const f16x8*)&ExT[(w * 32 +      l15) * LDA + io];
        const f16x8 bf1 = *(const f16x8*)&ExT[(w * 32 + 16 + l15) * LDA + io];
#pragma unroll
        for (int c = 0; c < 3; ++c) {
            const f16x8 a0 = *(const f16x8*)&Ey3[(c * 32 +      l15) * LDA + io];
            const f16x8 a1 = *(const f16x8*)&Ey3[(c * 32 + 16 + l15) * LDA + io];
            acc[c*4+0] = __builtin_amdgcn_mfma_f32_16x16x32_f16(a0, bf0, acc[c*4+0], 0, 0, 0);
            acc[c*4+1] = __builtin_amdgcn_mfma_f32_16x16x32_f16(a0, bf1, acc[c*4+1], 0, 0, 0);
            acc[c*4+2] = __builtin_amdgcn_mfma_f32_16x16x32_f16(a1, bf0, acc[c*4+2], 0, 0, 0);
            acc[c*4+3] = __builtin_amdgcn_mfma_f32_16x16x32_f16(a1, bf1, acc[c*4+3], 0, 0, 0);
        }
    }

    // ---- fragment-native fp16 partial store: lane-contiguous h4, coalesced.
    f16* P = wsP + (size_t)(tile * NSPLIT + sidx) * PBLK;
#pragma unroll
    for (int f = 0; f < 12; ++f) {
        f16x4 pv;
        pv[0] = (f16)acc[f][0];  pv[1] = (f16)acc[f][1];
        pv[2] = (f16)acc[f][2];  pv[3] = (f16)acc[f][3];
        *(f16x4*)&P[((w * 12 + f) * 64 + lane) * 4] = pv;
    }
}

// ---------------------------------------------------------------------------
// Reduce + normalize. Block bx = (tile, w, q=kt*2+jt): 64 blocks x 256 thr.
// Thread (lane = t&63, sq = t>>6) sums 32 splits x 3 channels of its h4 slot
// (8B loads, lane-consecutive -> fully coalesced); 4-way LDS combine; 64
// lanes normalize in-register (all 3 channels local) and write 12 outputs.
// ---------------------------------------------------------------------------
__global__ __launch_bounds__(256) void reduce_norm(
    const f16* __restrict__ wsP, float* __restrict__ out)
{
    __shared__ f32x4 sm[4][3][64];     // [sq][c][lane] : 12 KB

    const int bx   = blockIdx.x;
    const int tile = bx >> 4;
    const int w    = (bx >> 2) & 3;
    const int q    = bx & 3;           // kt*2 + jt
    const int t    = threadIdx.x;
    const int lane = t & 63;
    const int sq   = t >> 6;

    const f16x4* base = (const f16x4*)wsP;   // h4 units; PBLK/4 = 3072 per s
    const int slot = (w * 12 + q) * 64 + lane;

    f32x4 s0 = {0.f,0.f,0.f,0.f}, s1 = s0, s2 = s0;
#pragma unroll 8
    for (int s = sq * 32; s < sq * 32 + 32; ++s) {
        const size_t bo = (size_t)(tile * NSPLIT + s) * 3072 + slot;
        const f16x4 h0 = base[bo];           // c=0 (offset c*256)
        const f16x4 h1 = base[bo + 256];     // c=1
        const f16x4 h2 = base[bo + 512];     // c=2
#pragma unroll
        for (int r = 0; r < 4; ++r) {
            s0[r] += (float)h0[r];
            s1[r] += (float)h1[r];
            s2[r] += (float)h2[r];
        }
    }
    sm[sq][0][lane] = s0;
    sm[sq][1][lane] = s1;
    sm[sq][2][lane] = s2;
    __syncthreads();

    if (t < 64) {
        f32x4 f0 = {0.f,0.f,0.f,0.f}, f1 = f0, f2 = f0;
#pragma unroll
        for (int u = 0; u < 4; ++u) {
#pragma unroll
            for (int r = 0; r < 4; ++r) {
                f0[r] += sm[u][0][t][r];
                f1[r] += sm[u][1][t][r];
                f2[r] += sm[u][2][t][r];
            }
        }
        const int k0 = tile * 32 + (q >> 1) * 16 + (t >> 4) * 4;
        const int j  = w * 32 + (q & 1) * 16 + (t & 15);
#pragma unroll
        for (int r = 0; r < 4; ++r) {
            const int   g   = (k0 + r) * 128 + j;
            const float inv = 1.0f / f0[r];
            out[g]               = f0[r];
            out[G_TOTAL + g]     = f1[r] * inv;
            out[2 * G_TOTAL + g] = f2[r] * inv;
        }
    }
}

// ---------------------------------------------------------------------------
extern "C" void kernel_launch(void* const* d_in, const int* in_sizes, int n_in,
                              void* d_out, int out_size, void* d_ws, size_t ws_size,
                              hipStream_t stream) {
    const float* X = (const float*)d_in[0];
    const float* Y = (const float*)d_in[1];
    float* out = (float*)d_out;
    f16*  wsP = (f16*)d_ws;

    enc_mfma<<<512, 256, 0, stream>>>(X, Y, wsP);   // 2 blocks/CU
    reduce_norm<<<64, 256, 0, stream>>>(wsP, out);
}

// Round 10
// 64.214 us; speedup vs baseline: 1.2236x; 1.0743x over previous
//
#include <hip/hip_runtime.h>

#define G_TOTAL 16384            // 128 x 128 grid
#define NPTS    8192
#define CI      128              // context points per block chunk (R9: 64)
#define NSPLIT  64               // 8192 / CI  -> grid 256 = 1 block/CU
#define LDA     136              // LDS row pitch in halves (128 + 8 pad)
#define PBLK    12288            // partial halves per block: 4w x 12f x 64l x 4r

typedef _Float16 f16;
typedef f16  f16x8 __attribute__((ext_vector_type(8)));
typedef f16  f16x4 __attribute__((ext_vector_type(4)));
typedef float f32x4 __attribute__((ext_vector_type(4)));

// Raw v_exp_f32 — args in [-40, 0]: no denormal/range fixup needed.
__device__ __forceinline__ float fast_exp2(float x) {
#if __has_builtin(__builtin_amdgcn_exp2f)
    return __builtin_amdgcn_exp2f(x);
#else
    float r; asm("v_exp_f32 %0, %1" : "=v"(r) : "v"(x)); return r;
#endif
}

// ---------------------------------------------------------------------------
// MFMA factorized kernel v2 (R9 core, halved split-K).
// R9 post-mortem: kernel-side 27us; MFMA swap saved only 5.8 -> residual sits
// in staging latency + the 12.6MB partial round-trip, not the contraction.
// This round: CI 64->128, NSPLIT 128->64, grid 256 (1 block/CU). Partials
// halve to 6.3MB; per-CU staging work unchanged (same total exps); MFMA/wave
// 24->48 (still trivial). Layouts identical to R9 (verified): A[m][k]:
// m=l&15, k=(l>>4)*8+e; B same; D: row=(l>>4)*4+r, col=l&15. Pitch 272B ->
// 2-way banks on b128 frag reads (free, m136).
// ---------------------------------------------------------------------------
__global__ __launch_bounds__(256) void enc_mfma(
    const float* __restrict__ X,   // (8192, 2) positions
    const float* __restrict__ Y,   // (8192, 2) labels
    f16* __restrict__ wsP)         // partials [tile][s][PBLK]
{
    __shared__ f16 ExT[128 * LDA];     // [j][i]    34.8 KB
    __shared__ f16 Ey3[3 * 32 * LDA];  // [c][k][i] 26.1 KB

    const int t    = threadIdx.x;
    const int b    = blockIdx.x;
    const int tile = b & 3;            // k band: kb = tile*32
    const int sidx = b >> 2;           // split 0..63
    const int c0   = sidx * CI;
    const int kb   = tile * 32;

    const float sc   = 0.84932184f;    // sqrt(0.5 * log2(e))
    const float step = 4.0f / 127.0f;

    const float2* X2 = (const float2*)X;
    const float2* Y2 = (const float2*)Y;

    // ---- stage ExT[j][i], fp16: thread -> (j = t>>1, 64-i half)
    {
        const int   j  = t >> 1, ih = (t & 1) * 64;
        const float gx = (-2.0f + step * (float)j) * sc;
#pragma unroll
        for (int u = 0; u < 8; ++u) {
            f16x8 v;
#pragma unroll
            for (int e = 0; e < 8; ++e) {
                const int   i = ih + u * 8 + e;
                const float d = gx - X2[c0 + i].x * sc;
                v[e] = (f16)fast_exp2(-d * d);
            }
            *(f16x8*)&ExT[j * LDA + ih + u * 8] = v;
        }
    }
    // ---- stage Ey3[c][k][i], channels baked: thread -> (k = t>>3, 16-i blk)
    {
        const int   k  = t >> 3, ib = (t & 7) * 16;
        const float gy = (2.0f - step * (float)(kb + k)) * sc;
#pragma unroll
        for (int u = 0; u < 2; ++u) {
            f16x8 v0, v1, v2;
#pragma unroll
            for (int e = 0; e < 8; ++e) {
                const int    i  = ib + u * 8 + e;
                const float  d  = gy - X2[c0 + i].y * sc;
                const float  ee = fast_exp2(-d * d);
                const float2 yv = Y2[c0 + i];
                v0[e] = (f16)ee;
                v1[e] = (f16)(ee * yv.x);
                v2[e] = (f16)(ee * yv.y);
            }
            *(f16x8*)&Ey3[(0 * 32 + k) * LDA + ib + u * 8] = v0;
            *(f16x8*)&Ey3[(1 * 32 + k) * LDA + ib + u * 8] = v1;
            *(f16x8*)&Ey3[(2 * 32 + k) * LDA + ib + u * 8] = v2;
        }
    }
    __syncthreads();

    // ---- MFMA: wave w owns j in [32w, 32w+32). 48 mfma per wave (4 ksteps).
    const int w    = t >> 6;
    const int lane = t & 63;
    const int l15  = lane & 15;
    const int lk8  = (lane >> 4) * 8;

    f32x4 acc[12];                     // [c*4 + kt*2 + jt]
#pragma unroll
    for (int z = 0; z < 12; ++z) acc[z] = (f32x4){0.f, 0.f, 0.f, 0.f};

#pragma unroll
    for (int ks = 0; ks < 4; ++ks) {
        const int io = ks * 32 + lk8;
        const f16x8 bf0 = *(const f16x8*)&ExT[(w * 32 +      l15) * LDA + io];
        const f16x8 bf1 = *(const f16x8*)&ExT[(w * 32 + 16 + l15) * LDA + io];
#pragma unroll
        for (int c = 0; c < 3; ++c) {
            const f16x8 a0 = *(const f16x8*)&Ey3[(c * 32 +      l15) * LDA + io];
            const f16x8 a1 = *(const f16x8*)&Ey3[(c * 32 + 16 + l15) * LDA + io];
            acc[c*4+0] = __builtin_amdgcn_mfma_f32_16x16x32_f16(a0, bf0, acc[c*4+0], 0, 0, 0);
            acc[c*4+1] = __builtin_amdgcn_mfma_f32_16x16x32_f16(a0, bf1, acc[c*4+1], 0, 0, 0);
            acc[c*4+2] = __builtin_amdgcn_mfma_f32_16x16x32_f16(a1, bf0, acc[c*4+2], 0, 0, 0);
            acc[c*4+3] = __builtin_amdgcn_mfma_f32_16x16x32_f16(a1, bf1, acc[c*4+3], 0, 0, 0);
        }
    }

    // ---- fragment-native fp16 partial store: lane-contiguous h4, coalesced.
    f16* P = wsP + (size_t)(tile * NSPLIT + sidx) * PBLK;
#pragma unroll
    for (int f = 0; f < 12; ++f) {
        f16x4 pv;
        pv[0] = (f16)acc[f][0];  pv[1] = (f16)acc[f][1];
        pv[2] = (f16)acc[f][2];  pv[3] = (f16)acc[f][3];
        *(f16x4*)&P[((w * 12 + f) * 64 + lane) * 4] = pv;
    }
}

// ---------------------------------------------------------------------------
// Reduce + normalize, 8-wave blocks. Block bx = (tile, w, q): 64 blocks x 512.
// Thread (lane = t&63, sq = t>>6) sums 8 splits x 3 channels of its h4 slot
// (coalesced 8B loads); 8-way LDS combine; 64 lanes normalize in-register and
// write 12 outputs each.
// ---------------------------------------------------------------------------
__global__ __launch_bounds__(512) void reduce_norm(
    const f16* __restrict__ wsP, float* __restrict__ out)
{
    __shared__ f32x4 sm[8][3][64];     // [sq][c][lane] : 24 KB

    const int bx   = blockIdx.x;
    const int tile = bx >> 4;
    const int w    = (bx >> 2) & 3;
    const int q    = bx & 3;           // kt*2 + jt
    const int t    = threadIdx.x;
    const int lane = t & 63;
    const int sq   = t >> 6;           // 0..7

    const f16x4* base = (const f16x4*)wsP;   // h4 units; PBLK/4 = 3072 per s
    const int slot = (w * 12 + q) * 64 + lane;

    f32x4 s0 = {0.f,0.f,0.f,0.f}, s1 = s0, s2 = s0;
#pragma unroll 8
    for (int s = sq * 8; s < sq * 8 + 8; ++s) {
        const size_t bo = (size_t)(tile * NSPLIT + s) * 3072 + slot;
        const f16x4 h0 = base[bo];           // c=0 (offset c*256)
        const f16x4 h1 = base[bo + 256];     // c=1
        const f16x4 h2 = base[bo + 512];     // c=2
#pragma unroll
        for (int r = 0; r < 4; ++r) {
            s0[r] += (float)h0[r];
            s1[r] += (float)h1[r];
            s2[r] += (float)h2[r];
        }
    }
    sm[sq][0][lane] = s0;
    sm[sq][1][lane] = s1;
    sm[sq][2][lane] = s2;
    __syncthreads();

    if (t < 64) {
        f32x4 f0 = {0.f,0.f,0.f,0.f}, f1 = f0, f2 = f0;
#pragma unroll
        for (int u = 0; u < 8; ++u) {
#pragma unroll
            for (int r = 0; r < 4; ++r) {
                f0[r] += sm[u][0][t][r];
                f1[r] += sm[u][1][t][r];
                f2[r] += sm[u][2][t][r];
            }
        }
        const int k0 = tile * 32 + (q >> 1) * 16 + (t >> 4) * 4;
        const int j  = w * 32 + (q & 1) * 16 + (t & 15);
#pragma unroll
        for (int r = 0; r < 4; ++r) {
            const int   g   = (k0 + r) * 128 + j;
            const float inv = 1.0f / f0[r];
            out[g]               = f0[r];
            out[G_TOTAL + g]     = f1[r] * inv;
            out[2 * G_TOTAL + g] = f2[r] * inv;
        }
    }
}

// ---------------------------------------------------------------------------
extern "C" void kernel_launch(void* const* d_in, const int* in_sizes, int n_in,
                              void* d_out, int out_size, void* d_ws, size_t ws_size,
                              hipStream_t stream) {
    const float* X = (const float*)d_in[0];
    const float* Y = (const float*)d_in[1];
    float* out = (float*)d_out;
    f16*  wsP = (f16*)d_ws;

    enc_mfma<<<256, 256, 0, stream>>>(X, Y, wsP);   // 1 block/CU
    reduce_norm<<<64, 512, 0, stream>>>(wsP, out);
}